// Round 6
// baseline (614.567 us; speedup 1.0000x reference)
//
#include <hip/hip_runtime.h>

// Problem constants (match reference)
namespace {
constexpr int Bc   = 4;
constexpr int Nc   = 16384;
constexpr int Kc   = 27;
constexpr int Pc   = 68;                 // padded cells/axis: coords -2..65
constexpr int P2c  = Pc * Pc;            // 4624
constexpr int P3c  = Pc * P2c;           // 314432
constexpr int NPts = Bc * Nc;            // 65536
constexpr int Tc   = NPts * Kc;          // 1,769,472
constexpr int FT   = Bc * P3c;           // 1,257,728 table ints
constexpr unsigned INFu = 0xFFFFFFFFu;
constexpr int GBLK = 512;                // grid: co-resident by capacity
constexpr int GTHR = 256;
constexpr int TT   = GBLK * GTHR;        // 131072 threads
constexpr int PPB  = NPts / GBLK;        // 128 points per block (exact)
constexpr int PLANES = Bc * Pc;          // 272 plane blocks
constexpr unsigned SPIN_CAP = 2000000u;  // bounded spin: fail, never hang
}

__device__ unsigned g_bar  = 0;   // monotone arrival counter (reset each call)
__device__ unsigned g_done = 0;   // exit counter for last-resetter protocol

__device__ __forceinline__ unsigned min3u(unsigned a, unsigned b, unsigned c) {
    return min(min(a, b), c);
}
__device__ __forceinline__ int cidx(int bb, int x, int y, int z) {
    return bb * P3c + ((x + 2) * Pc + (y + 2)) * Pc + (z + 2);
}

// Grid barrier: all 512 blocks are co-resident (2/CU needed; LDS allows 4,
// launch_bounds caps VGPR<=256 -> >=2). Bounded spin => no-hang guarantee.
__device__ __forceinline__ void gbarrier(unsigned target, bool last) {
    __syncthreads();
    if (threadIdx.x == 0) {
        __threadfence();                       // release: drain writes (L2 wb)
        atomicAdd(&g_bar, 1u);
        unsigned spins = 0;
        while (__hip_atomic_load(&g_bar, __ATOMIC_ACQUIRE,
                                 __HIP_MEMORY_SCOPE_AGENT) < target) {
            __builtin_amdgcn_s_sleep(8);
            if (++spins > SPIN_CAP) break;     // safety valve
        }
        if (last) {                            // last exiter resets counters
            unsigned old = atomicAdd(&g_done, 1u);
            if (old == GBLK - 1) {
                __hip_atomic_store(&g_bar, 0u, __ATOMIC_RELAXED,
                                   __HIP_MEMORY_SCOPE_AGENT);
                __hip_atomic_store(&g_done, 0u, __ATOMIC_RELAXED,
                                   __HIP_MEMORY_SCOPE_AGENT);
            }
        }
    }
    __syncthreads();
    __threadfence();                           // acquire: invalidate caches
}

__global__ void __launch_bounds__(GTHR, 2)
mega_kernel(const int* __restrict__ coords, const int* __restrict__ batch,
            int* __restrict__ in_idx, int* __restrict__ out_idx,
            int* __restrict__ rel_pos, int* __restrict__ out_key,
            int* __restrict__ num_out,
            unsigned* __restrict__ cm, unsigned* __restrict__ Btab,
            int* __restrict__ rtab, int* __restrict__ blockSums) {
    __shared__ union {
        struct { unsigned s0[P2c]; unsigned s1[P2c]; } pl;       // 37 KB
        struct { int parts[64][4]; int pb[PPB]; int red[GTHR];
                 int scan[GTHR]; } ms;
    } sh;
    const int tid = threadIdx.x;
    const int bid = blockIdx.x;
    const int g   = bid * GTHR + tid;

    // ---- P0: init cell-min table to INF (int4) ----
    {
        int4 iv = make_int4(-1, -1, -1, -1);   // 0xFFFFFFFF
        const int n4 = FT / 4;                 // 314,432
        for (int i = g; i < n4; i += TT)
            reinterpret_cast<int4*>(cm)[i] = iv;
    }
    gbarrier(1 * GBLK, false);

    // ---- PA: one atomicMin per point ----
    if (g < NPts) {
        const int bb = batch[g];
        const int x = coords[3 * g], y = coords[3 * g + 1], z = coords[3 * g + 2];
        atomicMin(&cm[cidx(bb, x, y, z)], (unsigned)(g & (Nc - 1)));
    }
    gbarrier(2 * GBLK, false);

    // ---- PB: plane z/y sliding-min (blocks < 272) || easy outputs (rest) ----
    if (bid < PLANES) {
        const int base = bid * P2c;            // == (bb*68+px)*P2c
        for (int i4 = tid; i4 < P2c / 4; i4 += GTHR)
            reinterpret_cast<uint4*>(sh.pl.s0)[i4] =
                reinterpret_cast<const uint4*>(cm + base)[i4];
        __syncthreads();
        for (int i = tid; i < P2c; i += GTHR) {
            const int col = i % Pc;
            unsigned v = INFu;
            if (col >= 1 && col <= 66)
                v = min3u(sh.pl.s0[i - 1], sh.pl.s0[i], sh.pl.s0[i + 1]);
            sh.pl.s1[i] = v;
        }
        __syncthreads();
        for (int i = tid; i < P2c; i += GTHR) {
            const int row = i / Pc;
            unsigned v = INFu;
            if (row >= 1 && row <= 66)
                v = min3u(sh.pl.s1[i - Pc], sh.pl.s1[i], sh.pl.s1[i + Pc]);
            Btab[base + i] = v;
        }
    } else {
        const int g2 = (bid - PLANES) * GTHR + tid;
        const int stride = (GBLK - PLANES) * GTHR;       // 61,440
        const int t4 = Tc / 4;                           // 442,368
        for (int i = g2; i < t4; i += stride) {
            const int t = 4 * i;
            int4 a, r;
            a.x = (t / Kc) & (Nc - 1);       r.x = t % Kc;
            a.y = ((t + 1) / Kc) & (Nc - 1); r.y = (t + 1) % Kc;
            a.z = ((t + 2) / Kc) & (Nc - 1); r.z = (t + 2) % Kc;
            a.w = ((t + 3) / Kc) & (Nc - 1); r.w = (t + 3) % Kc;
            reinterpret_cast<int4*>(in_idx)[i]  = a;
            reinterpret_cast<int4*>(rel_pos)[i] = r;
        }
    }
    gbarrier(3 * GBLK, false);

    // ---- PC: predicate bits (4 threads/point, 2 halves of 64 points) ----
    for (int h = 0; h < 2; ++h) {
        const int p = tid >> 2, j = tid & 3;
        const int pt = bid * PPB + h * 64 + p;
        int pb = 0;
        if (j < 3) {
            const unsigned uidx = (unsigned)(pt & (Nc - 1));
            const int bb = batch[pt];
            const int x = coords[3 * pt], y = coords[3 * pt + 1],
                      z = coords[3 * pt + 2];
            const unsigned* basep =
                Btab + bb * P3c + (x * Pc + (y + j + 1)) * Pc + (z + 1);
            unsigned w[5][3];
            #pragma unroll
            for (int xi = 0; xi < 5; ++xi) {
                const unsigned* q = basep + xi * P2c;
                w[xi][0] = q[0]; w[xi][1] = q[1]; w[xi][2] = q[2];
            }
            #pragma unroll
            for (int dxl = 0; dxl < 3; ++dxl)
                #pragma unroll
                for (int dz = 0; dz < 3; ++dz) {
                    unsigned m = min3u(w[dxl][dz], w[dxl + 1][dz], w[dxl + 2][dz]);
                    pb |= (m == uidx) ? (1 << ((dxl * 3 + j) * 3 + dz)) : 0;
                }
        }
        sh.ms.parts[p][j] = pb;
        __syncthreads();
        if (j == 0)
            sh.ms.pb[h * 64 + p] =
                sh.ms.parts[p][0] | sh.ms.parts[p][1] | sh.ms.parts[p][2];
        __syncthreads();
    }
    {
        int v = (tid < PPB) ? __popc(sh.ms.pb[tid]) : 0;
        sh.ms.red[tid] = v;
        __syncthreads();
        for (int off = GTHR / 2; off > 0; off >>= 1) {
            if (tid < off) sh.ms.red[tid] += sh.ms.red[tid + off];
            __syncthreads();
        }
        if (tid == 0) blockSums[bid] = sh.ms.red[0];
    }
    gbarrier(4 * GBLK, false);

    // ---- PD: global scan + scatter rank/out_key + tail fill + num_out ----
    int total;
    {
        const int2 pr = reinterpret_cast<const int2*>(blockSums)[tid];
        const int s = pr.x + pr.y;
        sh.ms.scan[tid] = s;
        __syncthreads();
        #pragma unroll
        for (int off = 1; off < GTHR; off <<= 1) {
            int u = (tid >= off) ? sh.ms.scan[tid - off] : 0;
            __syncthreads();
            sh.ms.scan[tid] += u;
            __syncthreads();
        }
        total = sh.ms.scan[GTHR - 1];
        int before = 0;
        if (bid >= 2) before = sh.ms.scan[bid / 2 - 1];
        if (bid & 1)  before += blockSums[bid - 1];
        __syncthreads();

        const int ps = (tid < PPB) ? __popc(sh.ms.pb[tid]) : 0;
        sh.ms.scan[tid] = ps;
        __syncthreads();
        #pragma unroll
        for (int off = 1; off < GTHR; off <<= 1) {
            int u = (tid >= off) ? sh.ms.scan[tid - off] : 0;
            __syncthreads();
            sh.ms.scan[tid] += u;
            __syncthreads();
        }
        if (tid < PPB) {
            int r = before + sh.ms.scan[tid] - ps;
            const int pt = bid * PPB + tid;
            const int pb = sh.ms.pb[tid];
            const int bb = batch[pt];
            const int x = coords[3 * pt], y = coords[3 * pt + 1],
                      z = coords[3 * pt + 2];
            #pragma unroll
            for (int dx = -1; dx <= 1; ++dx)
                #pragma unroll
                for (int dy = -1; dy <= 1; ++dy)
                    #pragma unroll
                    for (int dz = -1; dz <= 1; ++dz) {
                        const int k = ((dx + 1) * 3 + (dy + 1)) * 3 + (dz + 1);
                        if ((pb >> k) & 1) {
                            const int cx = x + dx, cy = y + dy, cz = z + dz;
                            rtab[cidx(bb, cx, cy, cz)] = r;
                            out_key[3 * r + 0] = cx;
                            out_key[3 * r + 1] = cy;
                            out_key[3 * r + 2] = cz;
                            ++r;
                        }
                    }
        }
        for (int row = total + g; row < Tc; row += TT) {
            out_key[3 * row + 0] = -1;
            out_key[3 * row + 1] = -1;
            out_key[3 * row + 2] = -1;
        }
        if (g == 0) num_out[0] = total;
    }
    gbarrier(5 * GBLK, true);

    // ---- PE: out_idx gather ----
    for (int t = g; t < Tc; t += TT) {
        const int pt = t / Kc;
        const int k  = t - pt * Kc;
        const int bb = batch[pt];
        const int x = coords[3 * pt], y = coords[3 * pt + 1],
                  z = coords[3 * pt + 2];
        const int dx = k / 9 - 1;
        const int dy = (k / 3) % 3 - 1;
        const int dz = k - (k / 3) * 3 - 1;
        out_idx[t] = rtab[cidx(bb, x + dx, y + dy, z + dz)];
    }
}

extern "C" void kernel_launch(void* const* d_in, const int* in_sizes, int n_in,
                              void* d_out, int out_size, void* d_ws, size_t ws_size,
                              hipStream_t stream) {
    const int* coords = (const int*)d_in[0];   // [B, N, 3]
    const int* batch  = (const int*)d_in[1];   // [B, N]
    int* out = (int*)d_out;
    int* in_idx  = out;                 // [T]
    int* out_idx = out + Tc;            // [T]
    int* rel_pos = out + 2 * Tc;        // [T]
    int* out_key = out + 3 * Tc;        // [T,3]
    int* num_out = out + 6 * Tc;        // [1]

    unsigned* ws = (unsigned*)d_ws;
    unsigned* cm        = ws;                   // FT
    unsigned* Btab      = ws + FT;              // FT
    int*      rtab      = (int*)(ws + 2 * FT);  // FT
    int*      blockSums = (int*)(ws + 3 * FT);  // GBLK

    mega_kernel<<<GBLK, GTHR, 0, stream>>>(coords, batch, in_idx, out_idx,
                                           rel_pos, out_key, num_out,
                                           cm, Btab, rtab, blockSums);
}

// Round 7
// 493.390 us; speedup vs baseline: 1.2456x; 1.2456x over previous
//
#include <hip/hip_runtime.h>

// Problem constants (match reference)
namespace {
constexpr int Bc   = 4;
constexpr int Nc   = 16384;
constexpr int Kc   = 27;
constexpr int Pc   = 68;                 // padded cells/axis: coords -2..65
constexpr int P2c  = Pc * Pc;            // 4624
constexpr int P3c  = Pc * P2c;           // 314432
constexpr int NPts = Bc * Nc;            // 65536
constexpr int Tc   = NPts * Kc;          // 1,769,472
constexpr int FT   = Bc * P3c;           // 1,257,728 table ints
constexpr unsigned INFu = 0xFFFFFFFFu;
constexpr int PLANES = Bc * Pc;          // 272 plane blocks
constexpr int CBLK = 1024;               // scan/scatter blocks (co-resident)
constexpr int CPTS = NPts / CBLK;        // 64 points per block
constexpr unsigned SPIN_CAP = 4000000u;  // bounded spin: fail, never hang
}

__device__ __forceinline__ unsigned min3u(unsigned a, unsigned b, unsigned c) {
    return min(min(a, b), c);
}
__device__ __forceinline__ int cidx(int bb, int x, int y, int z) {
    return bb * P3c + ((x + 2) * Pc + (y + 2)) * Pc + (z + 2);
}

// K0: init cell-min table to INF; zero look-back states
__global__ void __launch_bounds__(256)
k0_init(unsigned* __restrict__ cm, unsigned long long* __restrict__ state) {
    const int g = blockIdx.x * 256 + threadIdx.x;
    const uint4 iv = make_uint4(INFu, INFu, INFu, INFu);
    const int n4 = FT / 4;                       // 314,432
    for (int i = g; i < n4; i += 512 * 256)
        reinterpret_cast<uint4*>(cm)[i] = iv;
    if (g < CBLK) state[g] = 0ull;
}

// K1: blocks 0..255: one atomicMin per point; all blocks: in_idx/rel_pos int4
__global__ void __launch_bounds__(256)
k1_atomic_easy(const int* __restrict__ coords, const int* __restrict__ batch,
               unsigned* __restrict__ cm,
               int* __restrict__ in_idx, int* __restrict__ rel_pos) {
    const int g = blockIdx.x * 256 + threadIdx.x;
    if (g < NPts) {
        const int bb = batch[g];
        const int x = coords[3 * g], y = coords[3 * g + 1], z = coords[3 * g + 2];
        atomicMin(&cm[cidx(bb, x, y, z)], (unsigned)(g & (Nc - 1)));
    }
    // grid is exactly Tc/4 threads: one int4 each
    const int t = 4 * g;
    int4 a, r;
    a.x = (t / Kc) & (Nc - 1);       r.x = t % Kc;
    a.y = ((t + 1) / Kc) & (Nc - 1); r.y = (t + 1) % Kc;
    a.z = ((t + 2) / Kc) & (Nc - 1); r.z = (t + 2) % Kc;
    a.w = ((t + 3) / Kc) & (Nc - 1); r.w = (t + 3) % Kc;
    reinterpret_cast<int4*>(in_idx)[g]  = a;
    reinterpret_cast<int4*>(rel_pos)[g] = r;
}

// K2: per (bb, px) plane: z-direction then y-direction sliding min via LDS
__global__ void __launch_bounds__(256)
k2_planes(const unsigned* __restrict__ cm, unsigned* __restrict__ Btab) {
    __shared__ unsigned s0[P2c];
    __shared__ unsigned s1[P2c];
    const int tid = threadIdx.x;
    const int base = blockIdx.x * P2c;
    for (int i4 = tid; i4 < P2c / 4; i4 += 256)
        reinterpret_cast<uint4*>(s0)[i4] =
            reinterpret_cast<const uint4*>(cm + base)[i4];
    __syncthreads();
    for (int i = tid; i < P2c; i += 256) {
        const int col = i % Pc;
        unsigned v = INFu;
        if (col >= 1 && col <= 66) v = min3u(s0[i - 1], s0[i], s0[i + 1]);
        s1[i] = v;
    }
    __syncthreads();
    for (int i = tid; i < P2c; i += 256) {
        const int row = i / Pc;
        unsigned v = INFu;
        if (row >= 1 && row <= 66) v = min3u(s1[i - Pc], s1[i], s1[i + Pc]);
        Btab[base + i] = v;
    }
}

// K3: predicate (4 thr/pt) + decoupled look-back scan + scatter rank/out_key
__global__ void __launch_bounds__(256)
k3_pred_scan_scatter(const int* __restrict__ coords, const int* __restrict__ batch,
                     const unsigned* __restrict__ Btab,
                     unsigned long long* __restrict__ state,
                     int* __restrict__ rtab, int* __restrict__ out_key,
                     int* __restrict__ num_out, int* __restrict__ total_ws) {
    __shared__ int parts[CPTS][4];
    __shared__ int pb[CPTS];
    __shared__ int scan[256];
    __shared__ int sbase;
    const int tid = threadIdx.x, bid = blockIdx.x;
    const int p = tid >> 2, j = tid & 3;
    const int pt = bid * CPTS + p;

    // predicate bits for this block's 64 points
    int mypb = 0;
    if (j < 3) {
        const unsigned uidx = (unsigned)(pt & (Nc - 1));
        const int bb = batch[pt];
        const int x = coords[3 * pt], y = coords[3 * pt + 1],
                  z = coords[3 * pt + 2];
        const unsigned* basep =
            Btab + bb * P3c + (x * Pc + (y + j + 1)) * Pc + (z + 1);
        unsigned w[5][3];
        #pragma unroll
        for (int xi = 0; xi < 5; ++xi) {
            const unsigned* q = basep + xi * P2c;
            w[xi][0] = q[0]; w[xi][1] = q[1]; w[xi][2] = q[2];
        }
        #pragma unroll
        for (int dxl = 0; dxl < 3; ++dxl)
            #pragma unroll
            for (int dz = 0; dz < 3; ++dz) {
                unsigned m = min3u(w[dxl][dz], w[dxl + 1][dz], w[dxl + 2][dz]);
                mypb |= (m == uidx) ? (1 << ((dxl * 3 + j) * 3 + dz)) : 0;
            }
    }
    parts[p][j] = mypb;
    __syncthreads();
    if (j == 0) pb[p] = parts[p][0] | parts[p][1] | parts[p][2];
    __syncthreads();

    // exclusive scan of the 64 popcounts (Hillis-Steele in LDS)
    const int v = (tid < CPTS) ? __popc(pb[tid]) : 0;
    scan[tid] = v;
    __syncthreads();
    #pragma unroll
    for (int off = 1; off < CPTS; off <<= 1) {
        int u = (tid >= off && tid < CPTS) ? scan[tid - off] : 0;
        __syncthreads();
        if (tid < CPTS) scan[tid] += u;
        __syncthreads();
    }
    const int agg = scan[CPTS - 1];

    // decoupled look-back (all 1024 blocks co-resident: ~3KB LDS, low VGPR)
    if (tid == 0) {
        if (bid > 0)
            __hip_atomic_store(&state[bid], (1ull << 32) | (unsigned)agg,
                               __ATOMIC_RELEASE, __HIP_MEMORY_SCOPE_AGENT);
        int excl = 0;
        if (bid > 0) {
            int jj = bid - 1;
            unsigned spins = 0;
            while (jj >= 0) {
                unsigned long long s =
                    __hip_atomic_load(&state[jj], __ATOMIC_ACQUIRE,
                                      __HIP_MEMORY_SCOPE_AGENT);
                const unsigned f = (unsigned)(s >> 32);
                if (f == 2u) { excl += (int)(unsigned)s; break; }
                if (f == 1u) { excl += (int)(unsigned)s; --jj; }
                else {
                    __builtin_amdgcn_s_sleep(1);
                    if (++spins > SPIN_CAP) break;   // fail, never hang
                }
            }
        }
        const int incl = excl + agg;
        __hip_atomic_store(&state[bid], (2ull << 32) | (unsigned)incl,
                           __ATOMIC_RELEASE, __HIP_MEMORY_SCOPE_AGENT);
        sbase = excl;
        if (bid == CBLK - 1) { num_out[0] = incl; total_ws[0] = incl; }
    }
    __syncthreads();

    // scatter rank table + out_key rows
    if (tid < CPTS) {
        int r = sbase + scan[tid] - v;
        const int mpb = pb[tid];
        const int bb = batch[pt];   // p == tid here? no: recompute for tid
        const int pt2 = bid * CPTS + tid;
        const int bb2 = batch[pt2];
        const int x = coords[3 * pt2], y = coords[3 * pt2 + 1],
                  z = coords[3 * pt2 + 2];
        (void)bb;
        #pragma unroll
        for (int dx = -1; dx <= 1; ++dx)
            #pragma unroll
            for (int dy = -1; dy <= 1; ++dy)
                #pragma unroll
                for (int dz = -1; dz <= 1; ++dz) {
                    const int k = ((dx + 1) * 3 + (dy + 1)) * 3 + (dz + 1);
                    if ((mpb >> k) & 1) {
                        const int cx = x + dx, cy = y + dy, cz = z + dz;
                        rtab[cidx(bb2, cx, cy, cz)] = r;
                        out_key[3 * r + 0] = cx;
                        out_key[3 * r + 1] = cy;
                        out_key[3 * r + 2] = cz;
                        ++r;
                    }
                }
    }
}

// K4: t-parallel out_idx gather + -1 tail fill of out_key
__global__ void __launch_bounds__(256)
k4_outputs(const int* __restrict__ coords, const int* __restrict__ batch,
           const int* __restrict__ rtab, const int* __restrict__ total_ws,
           int* __restrict__ out_idx, int* __restrict__ out_key) {
    const int t = blockIdx.x * 256 + threadIdx.x;
    const int pt = t / Kc;
    const int k  = t - Kc * pt;
    const int bb = batch[pt];
    const int x = coords[3 * pt], y = coords[3 * pt + 1], z = coords[3 * pt + 2];
    const int dx = k / 9 - 1;
    const int dy = (k / 3) % 3 - 1;
    const int dz = k - (k / 3) * 3 - 1;
    out_idx[t] = rtab[cidx(bb, x + dx, y + dy, z + dz)];
    if (t >= total_ws[0]) {
        out_key[3 * t + 0] = -1;
        out_key[3 * t + 1] = -1;
        out_key[3 * t + 2] = -1;
    }
}

extern "C" void kernel_launch(void* const* d_in, const int* in_sizes, int n_in,
                              void* d_out, int out_size, void* d_ws, size_t ws_size,
                              hipStream_t stream) {
    const int* coords = (const int*)d_in[0];   // [B, N, 3]
    const int* batch  = (const int*)d_in[1];   // [B, N]
    int* out = (int*)d_out;
    int* in_idx  = out;                 // [T]
    int* out_idx = out + Tc;            // [T]
    int* rel_pos = out + 2 * Tc;        // [T]
    int* out_key = out + 3 * Tc;        // [T,3]
    int* num_out = out + 6 * Tc;        // [1]

    unsigned* ws = (unsigned*)d_ws;
    unsigned* cm   = ws;                                  // FT
    unsigned* Btab = ws + FT;                             // FT
    int*      rtab = (int*)(ws + 2 * FT);                 // FT
    unsigned long long* state =
        (unsigned long long*)(ws + 3 * FT + (FT & 1));    // CBLK (8B aligned)
    int* total_ws = (int*)(state + CBLK);                 // 1

    k0_init<<<512, 256, 0, stream>>>(cm, state);
    k1_atomic_easy<<<Tc / 4 / 256, 256, 0, stream>>>(coords, batch, cm,
                                                     in_idx, rel_pos);
    k2_planes<<<PLANES, 256, 0, stream>>>(cm, Btab);
    k3_pred_scan_scatter<<<CBLK, 256, 0, stream>>>(coords, batch, Btab, state,
                                                   rtab, out_key, num_out,
                                                   total_ws);
    k4_outputs<<<Tc / 256, 256, 0, stream>>>(coords, batch, rtab, total_ws,
                                             out_idx, out_key);
}

// Round 9
// 106.676 us; speedup vs baseline: 5.7610x; 4.6251x over previous
//
#include <hip/hip_runtime.h>

// Problem constants (match reference)
namespace {
constexpr int Bc   = 4;
constexpr int Nc   = 16384;
constexpr int Kc   = 27;
constexpr int Pc   = 68;                 // padded cells/axis: coords -2..65
constexpr int P2c  = Pc * Pc;            // 4624
constexpr int P3c  = Pc * P2c;           // 314432
constexpr int NPts = Bc * Nc;            // 65536
constexpr int Tc   = NPts * Kc;          // 1,769,472
constexpr int FT   = Bc * P3c;           // 1,257,728 table ints
constexpr unsigned INFu = 0xFFFFFFFFu;
constexpr int PLANES = Bc * Pc;          // 272 plane blocks
constexpr int PBLKS  = 1024;             // predicate blocks
constexpr int PPTS   = NPts / PBLKS;     // 64 points per pred block
}

__device__ __forceinline__ unsigned min3u(unsigned a, unsigned b, unsigned c) {
    return min(min(a, b), c);
}
__device__ __forceinline__ int cidx(int bb, int x, int y, int z) {
    return bb * P3c + ((x + 2) * Pc + (y + 2)) * Pc + (z + 2);
}

// K0: init cell-min table to INF
__global__ void __launch_bounds__(256)
k0_init(unsigned* __restrict__ cm) {
    const int g = blockIdx.x * 256 + threadIdx.x;
    const uint4 iv = make_uint4(INFu, INFu, INFu, INFu);
    const int n4 = FT / 4;                       // 314,432
    for (int i = g; i < n4; i += 256 * 256)
        reinterpret_cast<uint4*>(cm)[i] = iv;
}

// K1: threads < NPts: one atomicMin per point; all threads: in_idx/rel_pos int4
__global__ void __launch_bounds__(256)
k1_atomic_easy(const int* __restrict__ coords, const int* __restrict__ batch,
               unsigned* __restrict__ cm,
               int* __restrict__ in_idx, int* __restrict__ rel_pos) {
    const int g = blockIdx.x * 256 + threadIdx.x;
    if (g < NPts) {
        const int bb = batch[g];
        const int x = coords[3 * g], y = coords[3 * g + 1], z = coords[3 * g + 2];
        atomicMin(&cm[cidx(bb, x, y, z)], (unsigned)(g & (Nc - 1)));
    }
    // grid is exactly Tc/4 threads: one int4 each
    const int t = 4 * g;
    int4 a, r;
    a.x = (t / Kc) & (Nc - 1);       r.x = t % Kc;
    a.y = ((t + 1) / Kc) & (Nc - 1); r.y = (t + 1) % Kc;
    a.z = ((t + 2) / Kc) & (Nc - 1); r.z = (t + 2) % Kc;
    a.w = ((t + 3) / Kc) & (Nc - 1); r.w = (t + 3) % Kc;
    reinterpret_cast<int4*>(in_idx)[g]  = a;
    reinterpret_cast<int4*>(rel_pos)[g] = r;
}

// K2: per (bb, px) plane: z-direction then y-direction sliding min via LDS
__global__ void __launch_bounds__(256)
k2_planes(const unsigned* __restrict__ cm, unsigned* __restrict__ Btab) {
    __shared__ unsigned s0[P2c];
    __shared__ unsigned s1[P2c];
    const int tid = threadIdx.x;
    const int base = blockIdx.x * P2c;
    for (int i4 = tid; i4 < P2c / 4; i4 += 256)
        reinterpret_cast<uint4*>(s0)[i4] =
            reinterpret_cast<const uint4*>(cm + base)[i4];
    __syncthreads();
    for (int i = tid; i < P2c; i += 256) {
        const int col = i % Pc;
        unsigned v = INFu;
        if (col >= 1 && col <= 66) v = min3u(s0[i - 1], s0[i], s0[i + 1]);
        s1[i] = v;
    }
    __syncthreads();
    for (int i = tid; i < P2c; i += 256) {
        const int row = i / Pc;
        unsigned v = INFu;
        if (row >= 1 && row <= 66) v = min3u(s1[i - Pc], s1[i], s1[i + Pc]);
        Btab[base + i] = v;
    }
}

// K3: predicate + owners (4 thr/pt): x-min in registers from Btab.
//     Writes owners[t] (window-min point idx per (pt,k)),
//     packed[pt] = predbits | intra_block_prefix<<27, blockSums[bid].
__global__ void __launch_bounds__(256)
k3_pred(const int* __restrict__ coords, const int* __restrict__ batch,
        const unsigned* __restrict__ Btab,
        int* __restrict__ owners, unsigned long long* __restrict__ packed,
        int* __restrict__ blockSums) {
    __shared__ int parts[PPTS][4];
    __shared__ int pbs[PPTS];
    __shared__ int scn[256];
    const int tid = threadIdx.x, bid = blockIdx.x;
    const int p = tid >> 2, j = tid & 3;
    const int pt = bid * PPTS + p;

    int mypb = 0;
    if (j < 3) {
        const unsigned uidx = (unsigned)(pt & (Nc - 1));
        const int bb = batch[pt];
        const int x = coords[3 * pt], y = coords[3 * pt + 1],
                  z = coords[3 * pt + 2];
        const unsigned* basep =
            Btab + bb * P3c + (x * Pc + (y + j + 1)) * Pc + (z + 1);
        unsigned w[5][3];
        #pragma unroll
        for (int xi = 0; xi < 5; ++xi) {
            const unsigned* q = basep + xi * P2c;
            w[xi][0] = q[0]; w[xi][1] = q[1]; w[xi][2] = q[2];
        }
        #pragma unroll
        for (int dxl = 0; dxl < 3; ++dxl)
            #pragma unroll
            for (int dz = 0; dz < 3; ++dz) {
                const unsigned m = min3u(w[dxl][dz], w[dxl + 1][dz],
                                         w[dxl + 2][dz]);
                const int kk = (dxl * 3 + j) * 3 + dz;
                owners[pt * Kc + kk] = (int)m;      // window always non-empty
                mypb |= (m == uidx) ? (1 << kk) : 0;
            }
    }
    parts[p][j] = mypb;
    __syncthreads();
    if (j == 0) pbs[p] = parts[p][0] | parts[p][1] | parts[p][2];
    __syncthreads();

    const int v = (tid < PPTS) ? __popc(pbs[tid]) : 0;
    scn[tid] = v;
    __syncthreads();
    #pragma unroll
    for (int off = 1; off < PPTS; off <<= 1) {
        int u = (tid >= off) ? scn[tid - off] : 0;
        __syncthreads();
        scn[tid] += u;
        __syncthreads();
    }
    if (tid < PPTS) {
        const int intra = scn[tid] - v;             // exclusive within block
        const int ptw = bid * PPTS + tid;           // FIX: point index is tid
        packed[ptw] = (unsigned long long)(unsigned)pbs[tid]
                    | ((unsigned long long)(unsigned)intra << 27);
    }
    if (tid == PPTS - 1) blockSums[bid] = scn[PPTS - 1];
}

// K4: grid-prefix in LDS (4KB), then per t: out_idx via owner lookup,
//     out_key scatter for own first-occurrences, tail fill, num_out.
__global__ void __launch_bounds__(256)
k4_outputs(const int* __restrict__ coords, const int* __restrict__ batch,
           const int* __restrict__ owners,
           const unsigned long long* __restrict__ packed,
           const int* __restrict__ blockSums,
           int* __restrict__ out_idx, int* __restrict__ out_key,
           int* __restrict__ num_out) {
    __shared__ int pref[PBLKS];     // exclusive prefix of the 1024 block sums
    __shared__ int scn[256];
    __shared__ int s_total;
    const int tid = threadIdx.x, bid = blockIdx.x;

    const int4 bsv = reinterpret_cast<const int4*>(blockSums)[tid];
    const int s = bsv.x + bsv.y + bsv.z + bsv.w;
    scn[tid] = s;
    __syncthreads();
    #pragma unroll
    for (int off = 1; off < 256; off <<= 1) {
        int u = (tid >= off) ? scn[tid - off] : 0;
        __syncthreads();
        scn[tid] += u;
        __syncthreads();
    }
    const int excl = scn[tid] - s;
    pref[4 * tid + 0] = excl;
    pref[4 * tid + 1] = excl + bsv.x;
    pref[4 * tid + 2] = excl + bsv.x + bsv.y;
    pref[4 * tid + 3] = excl + bsv.x + bsv.y + bsv.z;
    if (tid == 255) s_total = scn[255];
    __syncthreads();

    const int t  = bid * 256 + tid;
    const int pt = t / Kc;
    const int k  = t - Kc * pt;
    const int bb = batch[pt];
    const int x = coords[3 * pt], y = coords[3 * pt + 1], z = coords[3 * pt + 2];
    const int dx = k / 9 - 1;
    const int dy = (k / 3) % 3 - 1;
    const int dz = k - (k / 3) * 3 - 1;
    const int cx = x + dx, cy = y + dy, cz = z + dz;

    // owner of this key: min point idx in the 3x3x3 window around c
    const int o  = owners[t];
    const int go = bb * Nc + o;
    const int ox = coords[3 * go], oy = coords[3 * go + 1],
              oz = coords[3 * go + 2];
    const int kp = (cx - ox + 1) * 9 + (cy - oy + 1) * 3 + (cz - oz + 1);
    const unsigned long long pk = packed[go];
    const int pbo    = (int)(pk & 0x7ffffffull);
    const int intrao = (int)(pk >> 27);
    out_idx[t] = pref[go >> 6] + intrao + __popc(pbo & ((1 << kp) - 1));

    // own first-occurrence -> out_key row
    const unsigned long long pkw = packed[pt];
    const int pbw = (int)(pkw & 0x7ffffffull);
    if ((pbw >> k) & 1) {
        const int r = pref[pt >> 6] + (int)(pkw >> 27)
                    + __popc(pbw & ((1 << k) - 1));
        out_key[3 * r + 0] = cx;
        out_key[3 * r + 1] = cy;
        out_key[3 * r + 2] = cz;
    }
    if (t >= s_total) {
        out_key[3 * t + 0] = -1;
        out_key[3 * t + 1] = -1;
        out_key[3 * t + 2] = -1;
    }
    if (t == 0) num_out[0] = s_total;
}

extern "C" void kernel_launch(void* const* d_in, const int* in_sizes, int n_in,
                              void* d_out, int out_size, void* d_ws, size_t ws_size,
                              hipStream_t stream) {
    const int* coords = (const int*)d_in[0];   // [B, N, 3]
    const int* batch  = (const int*)d_in[1];   // [B, N]
    int* out = (int*)d_out;
    int* in_idx  = out;                 // [T]
    int* out_idx = out + Tc;            // [T]
    int* rel_pos = out + 2 * Tc;        // [T]
    int* out_key = out + 3 * Tc;        // [T,3]
    int* num_out = out + 6 * Tc;        // [1]

    unsigned* ws = (unsigned*)d_ws;
    unsigned* cm   = ws;                                   // FT ints
    unsigned* Btab = ws + FT;                              // FT ints
    unsigned long long* packed =
        (unsigned long long*)(ws + 2 * FT);                // NPts u64 (8B align)
    int* owners    = (int*)(packed + NPts);                // Tc ints
    int* blockSums = owners + Tc;                          // PBLKS ints

    k0_init<<<256, 256, 0, stream>>>(cm);
    k1_atomic_easy<<<Tc / 4 / 256, 256, 0, stream>>>(coords, batch, cm,
                                                     in_idx, rel_pos);
    k2_planes<<<PLANES, 256, 0, stream>>>(cm, Btab);
    k3_pred<<<PBLKS, 256, 0, stream>>>(coords, batch, Btab,
                                       owners, packed, blockSums);
    k4_outputs<<<Tc / 256, 256, 0, stream>>>(coords, batch, owners, packed,
                                             blockSums, out_idx, out_key,
                                             num_out);
}

// Round 10
// 101.700 us; speedup vs baseline: 6.0429x; 1.0489x over previous
//
#include <hip/hip_runtime.h>

// Problem constants (match reference)
namespace {
constexpr int Bc   = 4;
constexpr int Nc   = 16384;
constexpr int Kc   = 27;
constexpr int Pc   = 68;                 // padded cells/axis: coords -2..65
constexpr int P2c  = Pc * Pc;            // 4624
constexpr int P3c  = Pc * P2c;           // 314432
constexpr int NPts = Bc * Nc;            // 65536
constexpr int Tc   = NPts * Kc;          // 1,769,472
constexpr int FT   = Bc * P3c;           // 1,257,728 table ints
constexpr unsigned INFu = 0xFFFFFFFFu;
constexpr int PLANES = Bc * Pc;          // 272 (bb, px) planes
constexpr int SLABS  = 4;                // sub-slabs per plane
constexpr int SROWS  = 17;               // output rows per slab (4*17=68)
constexpr int PBLKS  = 1024;             // predicate blocks
constexpr int PPTS   = NPts / PBLKS;     // 64 points per pred block
constexpr int OBLKS  = 1728;             // k4 blocks
constexpr int OCHUNK = 4;                // k4 grid-stride chunks (1728*1024=Tc)
}

__device__ __forceinline__ unsigned min3u(unsigned a, unsigned b, unsigned c) {
    return min(min(a, b), c);
}
__device__ __forceinline__ int cidx(int bb, int x, int y, int z) {
    return bb * P3c + ((x + 2) * Pc + (y + 2)) * Pc + (z + 2);
}

// K0: init cell-min table to INF
__global__ void __launch_bounds__(256)
k0_init(unsigned* __restrict__ cm) {
    const int g = blockIdx.x * 256 + threadIdx.x;
    const uint4 iv = make_uint4(INFu, INFu, INFu, INFu);
    const int n4 = FT / 4;                       // 314,432
    for (int i = g; i < n4; i += 256 * 256)
        reinterpret_cast<uint4*>(cm)[i] = iv;
}

// K1: threads < NPts: one atomicMin per point; all threads: in_idx/rel_pos int4
__global__ void __launch_bounds__(256)
k1_atomic_easy(const int* __restrict__ coords, const int* __restrict__ batch,
               unsigned* __restrict__ cm,
               int* __restrict__ in_idx, int* __restrict__ rel_pos) {
    const int g = blockIdx.x * 256 + threadIdx.x;
    if (g < NPts) {
        const int bb = batch[g];
        const int x = coords[3 * g], y = coords[3 * g + 1], z = coords[3 * g + 2];
        atomicMin(&cm[cidx(bb, x, y, z)], (unsigned)(g & (Nc - 1)));
    }
    // grid is exactly Tc/4 threads: one int4 each
    const int t = 4 * g;
    int4 a, r;
    a.x = (t / Kc) & (Nc - 1);       r.x = t % Kc;
    a.y = ((t + 1) / Kc) & (Nc - 1); r.y = (t + 1) % Kc;
    a.z = ((t + 2) / Kc) & (Nc - 1); r.z = (t + 2) % Kc;
    a.w = ((t + 3) / Kc) & (Nc - 1); r.w = (t + 3) % Kc;
    reinterpret_cast<int4*>(in_idx)[g]  = a;
    reinterpret_cast<int4*>(rel_pos)[g] = r;
}

// K2: per (plane, slab): z-min then y-min via LDS. 1088 blocks for latency
//     hiding. Each block outputs SROWS rows, loads SROWS+2 halo rows.
__global__ void __launch_bounds__(256)
k2_planes(const unsigned* __restrict__ cm, unsigned* __restrict__ Btab) {
    __shared__ unsigned s1[(SROWS + 2) * Pc];    // z-min of loaded rows
    const int tid  = threadIdx.x;
    const int p    = blockIdx.x / SLABS;         // plane index
    const int slab = blockIdx.x - p * SLABS;
    const int r0   = slab * SROWS;               // first output row
    const int base = p * P2c;

    // load rows r0-1 .. r0+SROWS (19 rows), compute z-min directly into s1
    {
        __shared__ unsigned s0[(SROWS + 2) * Pc];
        const int n4 = (SROWS + 2) * Pc / 4;     // 323 uint4
        for (int i4 = tid; i4 < n4; i4 += 256) {
            const int li  = 4 * i4;
            const int row = r0 - 1 + li / Pc;    // global row of this int4
            uint4 v = make_uint4(INFu, INFu, INFu, INFu);
            if (row >= 0 && row < Pc)
                v = reinterpret_cast<const uint4*>(
                        cm + base + (row - (r0 - 1)) * 0 + row * Pc)[i4 % (Pc / 4)];
            reinterpret_cast<uint4*>(s0)[i4] = v;
        }
        __syncthreads();
        for (int i = tid; i < (SROWS + 2) * Pc; i += 256) {
            const int col = i % Pc;
            unsigned v = INFu;
            if (col >= 1 && col <= 66) v = min3u(s0[i - 1], s0[i], s0[i + 1]);
            s1[i] = v;
        }
        __syncthreads();
    }
    // y-min for output rows r0..r0+SROWS-1
    for (int i = tid; i < SROWS * Pc; i += 256) {
        const int lr  = i / Pc;                  // 0..16
        const int col = i - lr * Pc;
        const int row = r0 + lr;                 // global row
        unsigned v = INFu;
        if (row >= 1 && row <= 66) {
            const int li = (lr + 1) * Pc + col;  // center in s1 (halo offset)
            v = min3u(s1[li - Pc], s1[li], s1[li + Pc]);
        }
        Btab[base + row * Pc + col] = v;
    }
}

// K3: predicate + owners (4 thr/pt): x-min in registers from Btab.
__global__ void __launch_bounds__(256)
k3_pred(const int* __restrict__ coords, const int* __restrict__ batch,
        const unsigned* __restrict__ Btab,
        int* __restrict__ owners, unsigned long long* __restrict__ packed,
        int* __restrict__ blockSums) {
    __shared__ int parts[PPTS][4];
    __shared__ int pbs[PPTS];
    __shared__ int scn[256];
    const int tid = threadIdx.x, bid = blockIdx.x;
    const int p = tid >> 2, j = tid & 3;
    const int pt = bid * PPTS + p;

    int mypb = 0;
    if (j < 3) {
        const unsigned uidx = (unsigned)(pt & (Nc - 1));
        const int bb = batch[pt];
        const int x = coords[3 * pt], y = coords[3 * pt + 1],
                  z = coords[3 * pt + 2];
        const unsigned* basep =
            Btab + bb * P3c + (x * Pc + (y + j + 1)) * Pc + (z + 1);
        unsigned w[5][3];
        #pragma unroll
        for (int xi = 0; xi < 5; ++xi) {
            const unsigned* q = basep + xi * P2c;
            w[xi][0] = q[0]; w[xi][1] = q[1]; w[xi][2] = q[2];
        }
        #pragma unroll
        for (int dxl = 0; dxl < 3; ++dxl)
            #pragma unroll
            for (int dz = 0; dz < 3; ++dz) {
                const unsigned m = min3u(w[dxl][dz], w[dxl + 1][dz],
                                         w[dxl + 2][dz]);
                const int kk = (dxl * 3 + j) * 3 + dz;
                owners[pt * Kc + kk] = (int)m;      // window always non-empty
                mypb |= (m == uidx) ? (1 << kk) : 0;
            }
    }
    parts[p][j] = mypb;
    __syncthreads();
    if (j == 0) pbs[p] = parts[p][0] | parts[p][1] | parts[p][2];
    __syncthreads();

    const int v = (tid < PPTS) ? __popc(pbs[tid]) : 0;
    scn[tid] = v;
    __syncthreads();
    #pragma unroll
    for (int off = 1; off < PPTS; off <<= 1) {
        int u = (tid >= off) ? scn[tid - off] : 0;
        __syncthreads();
        scn[tid] += u;
        __syncthreads();
    }
    if (tid < PPTS) {
        const int intra = scn[tid] - v;             // exclusive within block
        packed[bid * PPTS + tid] = (unsigned long long)(unsigned)pbs[tid]
                                 | ((unsigned long long)(unsigned)intra << 27);
    }
    if (tid == PPTS - 1) blockSums[bid] = scn[PPTS - 1];
}

// K4: grid prefix in LDS once per block, then 4 contiguous chunks of 256 t's:
//     out_idx via owner lookup, out_key scatter, tail fill, num_out.
__global__ void __launch_bounds__(256)
k4_outputs(const int* __restrict__ coords, const int* __restrict__ batch,
           const int* __restrict__ owners,
           const unsigned long long* __restrict__ packed,
           const int* __restrict__ blockSums,
           int* __restrict__ out_idx, int* __restrict__ out_key,
           int* __restrict__ num_out) {
    __shared__ int pref[PBLKS];     // exclusive prefix of the 1024 block sums
    __shared__ int scn[256];
    __shared__ int s_total;
    const int tid = threadIdx.x, bid = blockIdx.x;

    const int4 bsv = reinterpret_cast<const int4*>(blockSums)[tid];
    const int s = bsv.x + bsv.y + bsv.z + bsv.w;
    scn[tid] = s;
    __syncthreads();
    #pragma unroll
    for (int off = 1; off < 256; off <<= 1) {
        int u = (tid >= off) ? scn[tid - off] : 0;
        __syncthreads();
        scn[tid] += u;
        __syncthreads();
    }
    const int excl = scn[tid] - s;
    pref[4 * tid + 0] = excl;
    pref[4 * tid + 1] = excl + bsv.x;
    pref[4 * tid + 2] = excl + bsv.x + bsv.y;
    pref[4 * tid + 3] = excl + bsv.x + bsv.y + bsv.z;
    if (tid == 255) s_total = scn[255];
    __syncthreads();

    const int total = s_total;
    #pragma unroll
    for (int c = 0; c < OCHUNK; ++c) {
        const int t  = bid * (256 * OCHUNK) + c * 256 + tid;
        const int pt = t / Kc;
        const int k  = t - Kc * pt;
        const int bb = batch[pt];
        const int x = coords[3 * pt], y = coords[3 * pt + 1],
                  z = coords[3 * pt + 2];
        const int dx = k / 9 - 1;
        const int dy = (k / 3) % 3 - 1;
        const int dz = k - (k / 3) * 3 - 1;
        const int cx = x + dx, cy = y + dy, cz = z + dz;

        // owner of this key: min point idx in the 3x3x3 window around c
        const int o  = owners[t];
        const int go = bb * Nc + o;
        const int ox = coords[3 * go], oy = coords[3 * go + 1],
                  oz = coords[3 * go + 2];
        const int kp = (cx - ox + 1) * 9 + (cy - oy + 1) * 3 + (cz - oz + 1);
        const unsigned long long pk = packed[go];
        const int pbo    = (int)(pk & 0x7ffffffull);
        const int intrao = (int)(pk >> 27);
        out_idx[t] = pref[go >> 6] + intrao + __popc(pbo & ((1 << kp) - 1));

        // own first-occurrence -> out_key row
        const unsigned long long pkw = packed[pt];
        const int pbw = (int)(pkw & 0x7ffffffull);
        if ((pbw >> k) & 1) {
            const int r = pref[pt >> 6] + (int)(pkw >> 27)
                        + __popc(pbw & ((1 << k) - 1));
            out_key[3 * r + 0] = cx;
            out_key[3 * r + 1] = cy;
            out_key[3 * r + 2] = cz;
        }
        if (t >= total) {
            out_key[3 * t + 0] = -1;
            out_key[3 * t + 1] = -1;
            out_key[3 * t + 2] = -1;
        }
        if (t == 0) num_out[0] = total;
    }
}

extern "C" void kernel_launch(void* const* d_in, const int* in_sizes, int n_in,
                              void* d_out, int out_size, void* d_ws, size_t ws_size,
                              hipStream_t stream) {
    const int* coords = (const int*)d_in[0];   // [B, N, 3]
    const int* batch  = (const int*)d_in[1];   // [B, N]
    int* out = (int*)d_out;
    int* in_idx  = out;                 // [T]
    int* out_idx = out + Tc;            // [T]
    int* rel_pos = out + 2 * Tc;        // [T]
    int* out_key = out + 3 * Tc;        // [T,3]
    int* num_out = out + 6 * Tc;        // [1]

    unsigned* ws = (unsigned*)d_ws;
    unsigned* cm   = ws;                                   // FT ints
    unsigned* Btab = ws + FT;                              // FT ints
    unsigned long long* packed =
        (unsigned long long*)(ws + 2 * FT);                // NPts u64 (8B align)
    int* owners    = (int*)(packed + NPts);                // Tc ints
    int* blockSums = owners + Tc;                          // PBLKS ints

    k0_init<<<256, 256, 0, stream>>>(cm);
    k1_atomic_easy<<<Tc / 4 / 256, 256, 0, stream>>>(coords, batch, cm,
                                                     in_idx, rel_pos);
    k2_planes<<<PLANES * SLABS, 256, 0, stream>>>(cm, Btab);
    k3_pred<<<PBLKS, 256, 0, stream>>>(coords, batch, Btab,
                                       owners, packed, blockSums);
    k4_outputs<<<OBLKS, 256, 0, stream>>>(coords, batch, owners, packed,
                                          blockSums, out_idx, out_key,
                                          num_out);
}